// Round 6
// baseline (275.178 us; speedup 1.0000x reference)
//
#include <hip/hip_runtime.h>

// Problem constants (powers of two -> shift/mask index math)
// B=32, C=3, H=512, W=512; H*W = 2^18, W = 2^9
#define IMG_B 32
#define IMG_C 3
#define IMG_H 512
#define IMG_W 512
#define HW_SHIFT 18
#define W_SHIFT 9

#define NBLOCKS_X (IMG_H * IMG_W / 256)   // 1024 pixel-blocks per image
#define NPARTIALS (NBLOCKS_X * IMG_B)     // 32768 per-block partial sums

// d_ws layout: [0, 2304)          : 64 inverted 3x3 matrices (32 pred, 32 true), 9 floats each
//                                   rows 0/1 pre-scaled by 512/511 (normalization folded in)
//              [2304, 2304+128K)  : per-block float partial sums (no atomics)
#define WS_INV_FLOATS (64 * 9)
#define WS_PART_OFFSET (WS_INV_FLOATS * sizeof(float))

__global__ void photoloss_invert_kernel(const float* __restrict__ Hp,
                                        const float* __restrict__ Ht,
                                        float* __restrict__ ws_inv) {
    int t = threadIdx.x;
    if (t < 64) {
        const float* src = (t < 32) ? (Hp + t * 9) : (Ht + (t - 32) * 9);
        float* dst = ws_inv + t * 9;
        // 3x3 inverse via adjugate, computed in double for conditioning.
        double a = src[0], b = src[1], c = src[2];
        double d = src[3], e = src[4], f = src[5];
        double g = src[6], h = src[7], i = src[8];
        double A = e * i - f * h;
        double Bc = c * h - b * i;
        double Cc = b * f - c * e;
        double D = f * g - d * i;
        double E = a * i - c * g;
        double F = c * d - a * f;
        double G = d * h - e * g;
        double Hh = b * g - a * h;
        double Ii = a * e - b * d;
        double idet = 1.0 / (a * A + b * D + c * G);
        // Fold the grid-normalization chain into rows 0/1:
        // xs = ((2X/(W-1)-1+1)*W-1)*0.5 = X*(W/(W-1)) - 0.5
        const double sc = (double)IMG_W / (double)(IMG_W - 1);  // 512/511 (H==W)
        dst[0] = (float)(A * idet * sc);
        dst[1] = (float)(Bc * idet * sc);
        dst[2] = (float)(Cc * idet * sc);
        dst[3] = (float)(D * idet * sc);
        dst[4] = (float)(E * idet * sc);
        dst[5] = (float)(F * idet * sc);
        dst[6] = (float)(G * idet);
        dst[7] = (float)(Hh * idet);
        dst[8] = (float)(Ii * idet);
    }
}

// One grid's sampling setup: 4 clamped byte offsets + 4 masked corner weights.
// Validity lives ONLY in the weights (per-axis select to exact 0.0f); offsets
// are clamped to [0, 2^19] so the buffer bounds check handles y-overflow
// (off*4 >= 2^20 -> returns 0) and no 32-bit wrap is possible.
__device__ __forceinline__ void grid_setup(float X, float Y, float Z,
                                           int* voff, float* w) {
    const float iz = __builtin_amdgcn_rcpf(Z);
    const float xs = __builtin_fmaf(X, iz, -0.5f);
    const float ys = __builtin_fmaf(Y, iz, -0.5f);

    const float x0f = __builtin_floorf(xs);
    const float y0f = __builtin_floorf(ys);
    const int x0 = (int)x0f, y0 = (int)y0f;
    const int x1 = (int)((unsigned)x0 + 1u);
    const int y1 = (int)((unsigned)y0 + 1u);

    float wx1 = xs - x0f, wx0 = 1.0f - wx1;
    float wy1 = ys - y0f, wy0 = 1.0f - wy1;
    // per-axis validity masking (select, not multiply: kills NaN/Inf cases too)
    wx0 = ((unsigned)x0 < (unsigned)IMG_W) ? wx0 : 0.0f;
    wx1 = ((unsigned)x1 < (unsigned)IMG_W) ? wx1 : 0.0f;
    wy0 = ((unsigned)y0 < (unsigned)IMG_H) ? wy0 : 0.0f;
    wy1 = ((unsigned)y1 < (unsigned)IMG_H) ? wy1 : 0.0f;

    w[0] = wx0 * wy0; w[1] = wx1 * wy0; w[2] = wx0 * wy1; w[3] = wx1 * wy1;

    const int base00 = (y0 << W_SHIFT) + x0;  // may wrap; clamped below
    const int lim = 1 << 19;
    int o00 = min(max(base00, 0), lim);
    int o10 = min(max(base00 + 1, 0), lim);
    int o01 = min(max(base00 + IMG_W, 0), lim);
    int o11 = min(max(base00 + IMG_W + 1, 0), lim);
    voff[0] = o00 << 2; voff[1] = o10 << 2; voff[2] = o01 << 2; voff[3] = o11 << 2;
}

__device__ __forceinline__ float buf_load_f32(__amdgpu_buffer_rsrc_t srd, int voff) {
    int r = __builtin_amdgcn_raw_buffer_load_b32(srd, voff, 0, 0);
    return __builtin_bit_cast(float, r);
}

__global__ __launch_bounds__(256) void photoloss_main_kernel(
        const float* __restrict__ I,
        const float* __restrict__ ws_inv,
        float* __restrict__ partials) {
    // XCD-aware batch-locality swizzle. Workgroups round-robin across the 8
    // XCDs by flat blockIdx (id%8 = XCD). Decode so one XCD processes one
    // batch image at a time (batch-major within XCD): its ~3 MB image stays
    // resident in the XCD's 4 MiB L2 instead of thrashing L3 across 8 XCDs.
    const int id = blockIdx.x;
    const int xcd = id & 7;
    const int idx = id >> 3;
    const int b = xcd + ((idx >> 10) << 3);   // {xcd, xcd+8, xcd+16, xcd+24}
    const int xblk = idx & (NBLOCKS_X - 1);

    const int p = xblk * 256 + threadIdx.x;  // pixel index within image
    const float fx = (float)(p & (IMG_W - 1));
    const float fy = (float)(p >> W_SHIFT);

    const float* __restrict__ hp = ws_inv + b * 9;          // pred inverse (rows 0/1 pre-scaled)
    const float* __restrict__ ht = ws_inv + (b + 32) * 9;   // true inverse

    // homography transforms (rows 0/1 carry the 512/511 normalization scale)
    const float Xp = __builtin_fmaf(hp[0], fx, __builtin_fmaf(hp[1], fy, hp[2]));
    const float Yp = __builtin_fmaf(hp[3], fx, __builtin_fmaf(hp[4], fy, hp[5]));
    const float Zp = __builtin_fmaf(hp[6], fx, __builtin_fmaf(hp[7], fy, hp[8]));
    const float Xt = __builtin_fmaf(ht[0], fx, __builtin_fmaf(ht[1], fy, ht[2]));
    const float Yt = __builtin_fmaf(ht[3], fx, __builtin_fmaf(ht[4], fy, ht[5]));
    const float Zt = __builtin_fmaf(ht[6], fx, __builtin_fmaf(ht[7], fy, ht[8]));

    int   voff[8];
    float wts[8];
    grid_setup(Xp, Yp, Zp, voff,     wts);
    grid_setup(Xt, Yt, Zt, voff + 4, wts + 4);

    const float* __restrict__ img = I + ((size_t)b * IMG_C << HW_SHIFT);
    // SRD per channel (2^20 bytes each). OOB voffset -> load returns 0.
    __amdgpu_buffer_rsrc_t srd0 = __builtin_amdgcn_make_buffer_rsrc(
        (void*)(img + ((size_t)0 << HW_SHIFT)), (short)0, IMG_H * IMG_W * 4, 0x00020000);
    __amdgpu_buffer_rsrc_t srd1 = __builtin_amdgcn_make_buffer_rsrc(
        (void*)(img + ((size_t)1 << HW_SHIFT)), (short)0, IMG_H * IMG_W * 4, 0x00020000);
    __amdgpu_buffer_rsrc_t srd2 = __builtin_amdgcn_make_buffer_rsrc(
        (void*)(img + ((size_t)2 << HW_SHIFT)), (short)0, IMG_H * IMG_W * 4, 0x00020000);

    // Batch all 24 buffer loads (one 32-bit voffset per corner, shared across
    // channels; SRD is SGPR) before any use.
    float v[IMG_C * 8];
#pragma unroll
    for (int k = 0; k < 8; ++k) v[0 * 8 + k] = buf_load_f32(srd0, voff[k]);
#pragma unroll
    for (int k = 0; k < 8; ++k) v[1 * 8 + k] = buf_load_f32(srd1, voff[k]);
#pragma unroll
    for (int k = 0; k < 8; ++k) v[2 * 8 + k] = buf_load_f32(srd2, voff[k]);

    float lsum = 0.0f;
#pragma unroll
    for (int c = 0; c < IMG_C; ++c) {
        const float* vc = v + c * 8;
        float vp = vc[0] * wts[0] + vc[1] * wts[1] + vc[2] * wts[2] + vc[3] * wts[3];
        float vt = vc[4] * wts[4] + vc[5] * wts[5] + vc[6] * wts[6] + vc[7] * wts[7];
        float d = vp - vt;
        lsum = __builtin_fmaf(d, d, lsum);
    }

    // wave (64-lane) reduction
#pragma unroll
    for (int off = 32; off > 0; off >>= 1)
        lsum += __shfl_down(lsum, off, 64);

    __shared__ float wsum[4];
    const int lane = threadIdx.x & 63;
    const int wid = threadIdx.x >> 6;
    if (lane == 0) wsum[wid] = lsum;
    __syncthreads();
    if (threadIdx.x == 0) {
        // One coalesced store per block -- NO atomics (same-address fp64
        // atomicAdd serialized the whole grid at ~400 us in R1/R2).
        partials[id] = wsum[0] + wsum[1] + wsum[2] + wsum[3];
    }
}

__global__ __launch_bounds__(1024) void photoloss_reduce_kernel(
        const float* __restrict__ partials, float* __restrict__ out) {
    // Single block, 1024 threads = 16 waves; 32 partials per thread.
    double s = 0.0;
    for (int i = threadIdx.x; i < NPARTIALS; i += 1024)
        s += (double)partials[i];
#pragma unroll
    for (int off = 32; off > 0; off >>= 1)
        s += __shfl_down(s, off, 64);

    __shared__ double wsum[16];
    const int lane = threadIdx.x & 63;
    const int wid = threadIdx.x >> 6;
    if (lane == 0) wsum[wid] = s;
    __syncthreads();
    if (threadIdx.x == 0) {
        double total = 0.0;
#pragma unroll
        for (int i = 0; i < 16; ++i) total += wsum[i];
        const double n = (double)IMG_B * IMG_C * IMG_H * IMG_W;  // 25165824
        out[0] = (float)(total / n);
    }
}

extern "C" void kernel_launch(void* const* d_in, const int* in_sizes, int n_in,
                              void* d_out, int out_size, void* d_ws, size_t ws_size,
                              hipStream_t stream) {
    const float* Hp = (const float*)d_in[0];
    const float* Ht = (const float*)d_in[1];
    const float* I  = (const float*)d_in[2];
    float* out = (float*)d_out;

    float* ws_inv = (float*)d_ws;
    float* partials = (float*)((char*)d_ws + WS_PART_OFFSET);

    photoloss_invert_kernel<<<1, 64, 0, stream>>>(Hp, Ht, ws_inv);

    photoloss_main_kernel<<<NPARTIALS, 256, 0, stream>>>(I, ws_inv, partials);

    photoloss_reduce_kernel<<<1, 1024, 0, stream>>>(partials, out);
}

// Round 7
// 209.827 us; speedup vs baseline: 1.3114x; 1.3114x over previous
//
#include <hip/hip_runtime.h>

// Problem constants (powers of two -> shift/mask index math)
// B=32, C=3, H=512, W=512; H*W = 2^18, W = 2^9
#define IMG_B 32
#define IMG_C 3
#define IMG_H 512
#define IMG_W 512
#define HW_SHIFT 18
#define W_SHIFT 9

// 2 px/thread: each block of 256 threads covers one full image row (512 px).
#define NBLOCKS_X IMG_H                   // 512 row-blocks per image
#define NPARTIALS (NBLOCKS_X * IMG_B)     // 16384 per-block partial sums

// d_ws layout: [0, 2304)         : 64 inverted 3x3 matrices (32 pred, 32 true), 9 floats each
//                                  rows 0/1 pre-scaled by 512/511 (normalization folded in)
//              [2304, 2304+64K)  : per-block float partial sums (no atomics)
#define WS_INV_FLOATS (64 * 9)
#define WS_PART_OFFSET (WS_INV_FLOATS * sizeof(float))

__global__ void photoloss_invert_kernel(const float* __restrict__ Hp,
                                        const float* __restrict__ Ht,
                                        float* __restrict__ ws_inv) {
    int t = threadIdx.x;
    if (t < 64) {
        const float* src = (t < 32) ? (Hp + t * 9) : (Ht + (t - 32) * 9);
        float* dst = ws_inv + t * 9;
        // 3x3 inverse via adjugate, computed in double for conditioning.
        double a = src[0], b = src[1], c = src[2];
        double d = src[3], e = src[4], f = src[5];
        double g = src[6], h = src[7], i = src[8];
        double A = e * i - f * h;
        double Bc = c * h - b * i;
        double Cc = b * f - c * e;
        double D = f * g - d * i;
        double E = a * i - c * g;
        double F = c * d - a * f;
        double G = d * h - e * g;
        double Hh = b * g - a * h;
        double Ii = a * e - b * d;
        double idet = 1.0 / (a * A + b * D + c * G);
        // Fold the grid-normalization chain into rows 0/1:
        // xs = ((2X/(W-1)-1+1)*W-1)*0.5 = X*(W/(W-1)) - 0.5
        const double sc = (double)IMG_W / (double)(IMG_W - 1);  // 512/511 (H==W)
        dst[0] = (float)(A * idet * sc);
        dst[1] = (float)(Bc * idet * sc);
        dst[2] = (float)(Cc * idet * sc);
        dst[3] = (float)(D * idet * sc);
        dst[4] = (float)(E * idet * sc);
        dst[5] = (float)(F * idet * sc);
        dst[6] = (float)(G * idet);
        dst[7] = (float)(Hh * idet);
        dst[8] = (float)(Ii * idet);
    }
}

// One grid's sampling setup: 4 clamped byte offsets + 4 masked corner weights.
// Validity lives ONLY in the weights (per-axis select to exact 0.0f); offsets
// are clamped to [0, 2^19] so the buffer bounds check handles y-overflow
// (off*4 >= 2^20 -> returns 0) and no 32-bit wrap is possible.
__device__ __forceinline__ void grid_setup(float X, float Y, float Z,
                                           int* voff, float* w) {
    const float iz = __builtin_amdgcn_rcpf(Z);
    const float xs = __builtin_fmaf(X, iz, -0.5f);
    const float ys = __builtin_fmaf(Y, iz, -0.5f);

    const float x0f = __builtin_floorf(xs);
    const float y0f = __builtin_floorf(ys);
    const int x0 = (int)x0f, y0 = (int)y0f;
    const int x1 = (int)((unsigned)x0 + 1u);
    const int y1 = (int)((unsigned)y0 + 1u);

    float wx1 = xs - x0f, wx0 = 1.0f - wx1;
    float wy1 = ys - y0f, wy0 = 1.0f - wy1;
    // per-axis validity masking (select, not multiply: kills NaN/Inf cases too)
    wx0 = ((unsigned)x0 < (unsigned)IMG_W) ? wx0 : 0.0f;
    wx1 = ((unsigned)x1 < (unsigned)IMG_W) ? wx1 : 0.0f;
    wy0 = ((unsigned)y0 < (unsigned)IMG_H) ? wy0 : 0.0f;
    wy1 = ((unsigned)y1 < (unsigned)IMG_H) ? wy1 : 0.0f;

    w[0] = wx0 * wy0; w[1] = wx1 * wy0; w[2] = wx0 * wy1; w[3] = wx1 * wy1;

    const int base00 = (y0 << W_SHIFT) + x0;  // may wrap; clamped below
    const int lim = 1 << 19;
    int o00 = min(max(base00, 0), lim);
    int o10 = min(max(base00 + 1, 0), lim);
    int o01 = min(max(base00 + IMG_W, 0), lim);
    int o11 = min(max(base00 + IMG_W + 1, 0), lim);
    voff[0] = o00 << 2; voff[1] = o10 << 2; voff[2] = o01 << 2; voff[3] = o11 << 2;
}

__device__ __forceinline__ float buf_load_f32(__amdgpu_buffer_rsrc_t srd, int voff) {
    int r = __builtin_amdgcn_raw_buffer_load_b32(srd, voff, 0, 0);
    return __builtin_bit_cast(float, r);
}

// 2 px/thread; __launch_bounds__(256,4) caps VGPR at 128 (4 waves/EU).
__global__ __launch_bounds__(256, 4) void photoloss_main_kernel(
        const float* __restrict__ I,
        const float* __restrict__ ws_inv,
        float* __restrict__ partials) {
    const int b = blockIdx.y;
    const int row = blockIdx.x;            // one full image row per block
    const int t = threadIdx.x;
    const float fy = (float)row;
    const float fx0 = (float)t;
    const float fx1 = (float)(t + 256);

    const float* __restrict__ hp = ws_inv + b * 9;          // pred inverse (rows 0/1 pre-scaled)
    const float* __restrict__ ht = ws_inv + (b + 32) * 9;   // true inverse

    // y-dependent part of each homography row is shared by both pixels
    const float cxp = __builtin_fmaf(hp[1], fy, hp[2]);
    const float cyp = __builtin_fmaf(hp[4], fy, hp[5]);
    const float czp = __builtin_fmaf(hp[7], fy, hp[8]);
    const float cxt = __builtin_fmaf(ht[1], fy, ht[2]);
    const float cyt = __builtin_fmaf(ht[4], fy, ht[5]);
    const float czt = __builtin_fmaf(ht[7], fy, ht[8]);

    int   voff[16];   // [0..3] px0-pred, [4..7] px0-true, [8..11] px1-pred, [12..15] px1-true
    float wts[16];
    grid_setup(__builtin_fmaf(hp[0], fx0, cxp), __builtin_fmaf(hp[3], fx0, cyp),
               __builtin_fmaf(hp[6], fx0, czp), voff + 0,  wts + 0);
    grid_setup(__builtin_fmaf(ht[0], fx0, cxt), __builtin_fmaf(ht[3], fx0, cyt),
               __builtin_fmaf(ht[6], fx0, czt), voff + 4,  wts + 4);
    grid_setup(__builtin_fmaf(hp[0], fx1, cxp), __builtin_fmaf(hp[3], fx1, cyp),
               __builtin_fmaf(hp[6], fx1, czp), voff + 8,  wts + 8);
    grid_setup(__builtin_fmaf(ht[0], fx1, cxt), __builtin_fmaf(ht[3], fx1, cyt),
               __builtin_fmaf(ht[6], fx1, czt), voff + 12, wts + 12);

    const float* __restrict__ img = I + ((size_t)b * IMG_C << HW_SHIFT);
    // SRD per channel (2^20 bytes each). OOB voffset -> load returns 0.
    __amdgpu_buffer_rsrc_t srd0 = __builtin_amdgcn_make_buffer_rsrc(
        (void*)(img + ((size_t)0 << HW_SHIFT)), (short)0, IMG_H * IMG_W * 4, 0x00020000);
    __amdgpu_buffer_rsrc_t srd1 = __builtin_amdgcn_make_buffer_rsrc(
        (void*)(img + ((size_t)1 << HW_SHIFT)), (short)0, IMG_H * IMG_W * 4, 0x00020000);
    __amdgpu_buffer_rsrc_t srd2 = __builtin_amdgcn_make_buffer_rsrc(
        (void*)(img + ((size_t)2 << HW_SHIFT)), (short)0, IMG_H * IMG_W * 4, 0x00020000);

    // Batch ALL 48 loads (2 px x 3 ch x 8 corners) before any use:
    // maximal loads in flight behind one vmcnt drain.
    float v[48];
#pragma unroll
    for (int k = 0; k < 16; ++k) v[0 * 16 + k] = buf_load_f32(srd0, voff[k]);
#pragma unroll
    for (int k = 0; k < 16; ++k) v[1 * 16 + k] = buf_load_f32(srd1, voff[k]);
#pragma unroll
    for (int k = 0; k < 16; ++k) v[2 * 16 + k] = buf_load_f32(srd2, voff[k]);

    float lsum = 0.0f;
#pragma unroll
    for (int c = 0; c < IMG_C; ++c) {
#pragma unroll
        for (int px = 0; px < 2; ++px) {
            const float* vc = v + c * 16 + px * 8;
            const float* wc = wts + px * 8;
            float vp = vc[0] * wc[0] + vc[1] * wc[1] + vc[2] * wc[2] + vc[3] * wc[3];
            float vt = vc[4] * wc[4] + vc[5] * wc[5] + vc[6] * wc[6] + vc[7] * wc[7];
            float d = vp - vt;
            lsum = __builtin_fmaf(d, d, lsum);
        }
    }

    // wave (64-lane) reduction
#pragma unroll
    for (int off = 32; off > 0; off >>= 1)
        lsum += __shfl_down(lsum, off, 64);

    __shared__ float wsum[4];
    const int lane = threadIdx.x & 63;
    const int wid = threadIdx.x >> 6;
    if (lane == 0) wsum[wid] = lsum;
    __syncthreads();
    if (threadIdx.x == 0) {
        // One coalesced store per block -- NO atomics (same-address fp64
        // atomicAdd serialized the whole grid at ~400 us in R1/R2).
        partials[blockIdx.y * gridDim.x + blockIdx.x] = wsum[0] + wsum[1] + wsum[2] + wsum[3];
    }
}

__global__ __launch_bounds__(1024) void photoloss_reduce_kernel(
        const float* __restrict__ partials, float* __restrict__ out) {
    // Single block, 1024 threads = 16 waves; 16 partials per thread.
    double s = 0.0;
    for (int i = threadIdx.x; i < NPARTIALS; i += 1024)
        s += (double)partials[i];
#pragma unroll
    for (int off = 32; off > 0; off >>= 1)
        s += __shfl_down(s, off, 64);

    __shared__ double wsum[16];
    const int lane = threadIdx.x & 63;
    const int wid = threadIdx.x >> 6;
    if (lane == 0) wsum[wid] = s;
    __syncthreads();
    if (threadIdx.x == 0) {
        double total = 0.0;
#pragma unroll
        for (int i = 0; i < 16; ++i) total += wsum[i];
        const double n = (double)IMG_B * IMG_C * IMG_H * IMG_W;  // 25165824
        out[0] = (float)(total / n);
    }
}

extern "C" void kernel_launch(void* const* d_in, const int* in_sizes, int n_in,
                              void* d_out, int out_size, void* d_ws, size_t ws_size,
                              hipStream_t stream) {
    const float* Hp = (const float*)d_in[0];
    const float* Ht = (const float*)d_in[1];
    const float* I  = (const float*)d_in[2];
    float* out = (float*)d_out;

    float* ws_inv = (float*)d_ws;
    float* partials = (float*)((char*)d_ws + WS_PART_OFFSET);

    photoloss_invert_kernel<<<1, 64, 0, stream>>>(Hp, Ht, ws_inv);

    dim3 grid(NBLOCKS_X, IMG_B);  // (512, 32), natural order (R6 XCD swizzle regressed)
    photoloss_main_kernel<<<grid, 256, 0, stream>>>(I, ws_inv, partials);

    photoloss_reduce_kernel<<<1, 1024, 0, stream>>>(partials, out);
}

// Round 9
// 199.799 us; speedup vs baseline: 1.3773x; 1.0502x over previous
//
#include <hip/hip_runtime.h>

// Problem constants (powers of two -> shift/mask index math)
// B=32, C=3, H=512, W=512; H*W = 2^18, W = 2^9
#define IMG_B 32
#define IMG_C 3
#define IMG_H 512
#define IMG_W 512
#define HW_SHIFT 18
#define W_SHIFT 9

// 2 px/thread: each block of 256 threads covers one full image row (512 px).
#define NBLOCKS_X IMG_H                   // 512 row-blocks per image
#define NPARTIALS (NBLOCKS_X * IMG_B)     // 16384 per-block partial sums

// d_ws layout: [0, 2304)         : 64 inverted 3x3 matrices (32 pred, 32 true), 9 floats each
//                                  rows 0/1 pre-scaled by 512/511 (normalization folded in)
//              [2304, 2304+64K)  : per-block float partial sums (no atomics)
#define WS_INV_FLOATS (64 * 9)
#define WS_PART_OFFSET (WS_INV_FLOATS * sizeof(float))

__global__ void photoloss_invert_kernel(const float* __restrict__ Hp,
                                        const float* __restrict__ Ht,
                                        float* __restrict__ ws_inv) {
    int t = threadIdx.x;
    if (t < 64) {
        const float* src = (t < 32) ? (Hp + t * 9) : (Ht + (t - 32) * 9);
        float* dst = ws_inv + t * 9;
        // 3x3 inverse via adjugate, computed in double for conditioning.
        double a = src[0], b = src[1], c = src[2];
        double d = src[3], e = src[4], f = src[5];
        double g = src[6], h = src[7], i = src[8];
        double A = e * i - f * h;
        double Bc = c * h - b * i;
        double Cc = b * f - c * e;
        double D = f * g - d * i;
        double E = a * i - c * g;
        double F = c * d - a * f;
        double G = d * h - e * g;
        double Hh = b * g - a * h;
        double Ii = a * e - b * d;
        double idet = 1.0 / (a * A + b * D + c * G);
        // Fold the grid-normalization chain into rows 0/1:
        // xs = ((2X/(W-1)-1+1)*W-1)*0.5 = X*(W/(W-1)) - 0.5
        const double sc = (double)IMG_W / (double)(IMG_W - 1);  // 512/511 (H==W)
        dst[0] = (float)(A * idet * sc);
        dst[1] = (float)(Bc * idet * sc);
        dst[2] = (float)(Cc * idet * sc);
        dst[3] = (float)(D * idet * sc);
        dst[4] = (float)(E * idet * sc);
        dst[5] = (float)(F * idet * sc);
        dst[6] = (float)(G * idet);
        dst[7] = (float)(Hh * idet);
        dst[8] = (float)(Ii * idet);
    }
}

// Paired-corner sampling setup. The two x-adjacent corners of each bilinear
// row are fetched with ONE 8-byte load (4B-aligned; global loads tolerate
// this on gfx950 -- MUBUF dwordx2 does NOT, which broke R8).
// E[0]/E[1] = clamped element indices of the (y0,y1) row pairs.
// W[0..3]  = weights for (row0.slotA, row0.slotB, row1.slotA, row1.slotB).
// Validity lives ONLY in the weights. Two slot-swap cases:
//  - left edge x0==-1: pair loaded at xc0=0, x1 corner sits in slot A.
//  - clamp-down e==H*W-1 (image corner): x0 corner sits in slot B.
__device__ __forceinline__ void grid_setup_pair(float X, float Y, float Z,
                                                int* E, float* W) {
    const float iz = __builtin_amdgcn_rcpf(Z);
    const float xs = __builtin_fmaf(X, iz, -0.5f);
    const float ys = __builtin_fmaf(Y, iz, -0.5f);

    const float x0f = __builtin_floorf(xs);
    const float y0f = __builtin_floorf(ys);
    const int x0 = (int)x0f, y0 = (int)y0f;
    const int x1 = x0 + 1, y1 = y0 + 1;

    float wx1 = xs - x0f, wx0 = 1.0f - wx1;
    float wy1 = ys - y0f, wy0 = 1.0f - wy1;
    const float wx0m = ((unsigned)x0 < (unsigned)IMG_W) ? wx0 : 0.0f;
    const float wx1m = ((unsigned)x1 < (unsigned)IMG_W) ? wx1 : 0.0f;
    const float wy0m = ((unsigned)y0 < (unsigned)IMG_H) ? wy0 : 0.0f;
    const float wy1m = ((unsigned)y1 < (unsigned)IMG_H) ? wy1 : 0.0f;

    const bool sl = (x0 < 0);               // x0==-1 => x1 corner in slot A
    const float xA = sl ? wx1m : wx0m;      // (x0<=-2 => wx1m==0 too)
    const float xB = sl ? 0.0f : wx1m;
    const int xc0 = min(max(x0, 0), IMG_W - 1);

    const int e0r = y0 * IMG_W + xc0;       // may be far out of range
    const int e1r = e0r + IMG_W;
    const int emax = IMG_H * IMG_W - 2;     // pair [emax, emax+1] is last valid
    const int e0 = min(max(e0r, 0), emax);
    const int e1 = min(max(e1r, 0), emax);
    // Clamp fired? Either y-invalid (y-weight 0, slots irrelevant) or the
    // genuine e==H*W-1 corner case (clamp-down by 1: x0 value in slot B).
    const bool d0 = (e0 != e0r);
    const bool d1 = (e1 != e1r);
    const float uA0 = d0 ? 0.0f : xA, uB0 = d0 ? xA : xB;
    const float uA1 = d1 ? 0.0f : xA, uB1 = d1 ? xA : xB;

    E[0] = e0;
    E[1] = e1;
    W[0] = uA0 * wy0m; W[1] = uB0 * wy0m;
    W[2] = uA1 * wy1m; W[3] = uB1 * wy1m;
}

// 8-byte load at 4-byte alignment: memcpy -> load <2 x float> align 4 ->
// global_load_dwordx2 (gfx950 supports unaligned global access).
__device__ __forceinline__ float2 load_pair(const float* p) {
    float2 r;
    __builtin_memcpy(&r, p, 8);
    return r;
}

// 2 px/thread; __launch_bounds__(256,4) caps VGPR at 128 (4 waves/EU).
__global__ __launch_bounds__(256, 4) void photoloss_main_kernel(
        const float* __restrict__ I,
        const float* __restrict__ ws_inv,
        float* __restrict__ partials) {
    const int b = blockIdx.y;
    const int row = blockIdx.x;            // one full image row per block
    const int t = threadIdx.x;
    const float fy = (float)row;
    const float fx0 = (float)t;
    const float fx1 = (float)(t + 256);

    const float* __restrict__ hp = ws_inv + b * 9;          // pred inverse (rows 0/1 pre-scaled)
    const float* __restrict__ ht = ws_inv + (b + 32) * 9;   // true inverse

    // y-dependent part of each homography row is shared by both pixels
    const float cxp = __builtin_fmaf(hp[1], fy, hp[2]);
    const float cyp = __builtin_fmaf(hp[4], fy, hp[5]);
    const float czp = __builtin_fmaf(hp[7], fy, hp[8]);
    const float cxt = __builtin_fmaf(ht[1], fy, ht[2]);
    const float cyt = __builtin_fmaf(ht[4], fy, ht[5]);
    const float czt = __builtin_fmaf(ht[7], fy, ht[8]);

    // combo j: 0=px0-pred, 1=px0-true, 2=px1-pred, 3=px1-true
    int   Eoff[8];    // [2j] = row-y0 pair element index, [2j+1] = row-y1
    float W[16];      // [4j..4j+3] = weights for that combo's 4 corners
    grid_setup_pair(__builtin_fmaf(hp[0], fx0, cxp), __builtin_fmaf(hp[3], fx0, cyp),
                    __builtin_fmaf(hp[6], fx0, czp), Eoff + 0, W + 0);
    grid_setup_pair(__builtin_fmaf(ht[0], fx0, cxt), __builtin_fmaf(ht[3], fx0, cyt),
                    __builtin_fmaf(ht[6], fx0, czt), Eoff + 2, W + 4);
    grid_setup_pair(__builtin_fmaf(hp[0], fx1, cxp), __builtin_fmaf(hp[3], fx1, cyp),
                    __builtin_fmaf(hp[6], fx1, czp), Eoff + 4, W + 8);
    grid_setup_pair(__builtin_fmaf(ht[0], fx1, cxt), __builtin_fmaf(ht[3], fx1, cyt),
                    __builtin_fmaf(ht[6], fx1, czt), Eoff + 6, W + 12);

    const float* __restrict__ ch0 = I + ((size_t)b * IMG_C << HW_SHIFT);
    const float* __restrict__ ch1 = ch0 + ((size_t)1 << HW_SHIFT);
    const float* __restrict__ ch2 = ch0 + ((size_t)2 << HW_SHIFT);

    // Batch ALL 24 paired loads (2px x 2 grids x 2 rows x 3 ch = 48 corner
    // values) before any use: half the gather *addresses* of the R7 version.
    float2 r[24];
#pragma unroll
    for (int k = 0; k < 8; ++k) r[0 * 8 + k] = load_pair(ch0 + Eoff[k]);
#pragma unroll
    for (int k = 0; k < 8; ++k) r[1 * 8 + k] = load_pair(ch1 + Eoff[k]);
#pragma unroll
    for (int k = 0; k < 8; ++k) r[2 * 8 + k] = load_pair(ch2 + Eoff[k]);

    float lsum = 0.0f;
#pragma unroll
    for (int c = 0; c < IMG_C; ++c) {
        const float2* rc = r + c * 8;
        const float sp0 = rc[0].x * W[0]  + rc[0].y * W[1]  + rc[1].x * W[2]  + rc[1].y * W[3];
        const float st0 = rc[2].x * W[4]  + rc[2].y * W[5]  + rc[3].x * W[6]  + rc[3].y * W[7];
        const float sp1 = rc[4].x * W[8]  + rc[4].y * W[9]  + rc[5].x * W[10] + rc[5].y * W[11];
        const float st1 = rc[6].x * W[12] + rc[6].y * W[13] + rc[7].x * W[14] + rc[7].y * W[15];
        const float d0 = sp0 - st0;
        const float d1 = sp1 - st1;
        lsum = __builtin_fmaf(d0, d0, lsum);
        lsum = __builtin_fmaf(d1, d1, lsum);
    }

    // wave (64-lane) reduction
#pragma unroll
    for (int off = 32; off > 0; off >>= 1)
        lsum += __shfl_down(lsum, off, 64);

    __shared__ float wsum[4];
    const int lane = threadIdx.x & 63;
    const int wid = threadIdx.x >> 6;
    if (lane == 0) wsum[wid] = lsum;
    __syncthreads();
    if (threadIdx.x == 0) {
        // One coalesced store per block -- NO atomics (same-address fp64
        // atomicAdd serialized the whole grid at ~400 us in R1/R2).
        partials[blockIdx.y * gridDim.x + blockIdx.x] = wsum[0] + wsum[1] + wsum[2] + wsum[3];
    }
}

__global__ __launch_bounds__(1024) void photoloss_reduce_kernel(
        const float* __restrict__ partials, float* __restrict__ out) {
    // Single block, 1024 threads = 16 waves; 16 partials per thread.
    double s = 0.0;
    for (int i = threadIdx.x; i < NPARTIALS; i += 1024)
        s += (double)partials[i];
#pragma unroll
    for (int off = 32; off > 0; off >>= 1)
        s += __shfl_down(s, off, 64);

    __shared__ double wsum[16];
    const int lane = threadIdx.x & 63;
    const int wid = threadIdx.x >> 6;
    if (lane == 0) wsum[wid] = s;
    __syncthreads();
    if (threadIdx.x == 0) {
        double total = 0.0;
#pragma unroll
        for (int i = 0; i < 16; ++i) total += wsum[i];
        const double n = (double)IMG_B * IMG_C * IMG_H * IMG_W;  // 25165824
        out[0] = (float)(total / n);
    }
}

extern "C" void kernel_launch(void* const* d_in, const int* in_sizes, int n_in,
                              void* d_out, int out_size, void* d_ws, size_t ws_size,
                              hipStream_t stream) {
    const float* Hp = (const float*)d_in[0];
    const float* Ht = (const float*)d_in[1];
    const float* I  = (const float*)d_in[2];
    float* out = (float*)d_out;

    float* ws_inv = (float*)d_ws;
    float* partials = (float*)((char*)d_ws + WS_PART_OFFSET);

    photoloss_invert_kernel<<<1, 64, 0, stream>>>(Hp, Ht, ws_inv);

    dim3 grid(NBLOCKS_X, IMG_B);  // (512, 32), natural order (R6 XCD swizzle regressed)
    photoloss_main_kernel<<<grid, 256, 0, stream>>>(I, ws_inv, partials);

    photoloss_reduce_kernel<<<1, 1024, 0, stream>>>(partials, out);
}

// Round 10
// 187.659 us; speedup vs baseline: 1.4664x; 1.0647x over previous
//
#include <hip/hip_runtime.h>

// Problem constants (powers of two -> shift/mask index math)
// B=32, C=3, H=512, W=512; H*W = 2^18, W = 2^9
#define IMG_B 32
#define IMG_C 3
#define IMG_H 512
#define IMG_W 512
#define HW_SHIFT 18
#define W_SHIFT 9

// 2 px/thread: each block of 256 threads covers one full image row (512 px).
#define NBLOCKS_X IMG_H                   // 512 row-blocks per image
#define NPARTIALS (NBLOCKS_X * IMG_B)     // 16384 per-block partial sums

// d_ws layout: [0, 2304)         : 64 inverted 3x3 matrices (32 pred, 32 true), 9 floats each
//                                  rows 0/1 pre-scaled by 512/511 (normalization folded in)
//              [2304, 2304+64K)  : per-block float partial sums (no atomics)
#define WS_INV_FLOATS (64 * 9)
#define WS_PART_OFFSET (WS_INV_FLOATS * sizeof(float))

__global__ void photoloss_invert_kernel(const float* __restrict__ Hp,
                                        const float* __restrict__ Ht,
                                        float* __restrict__ ws_inv) {
    int t = threadIdx.x;
    if (t < 64) {
        const float* src = (t < 32) ? (Hp + t * 9) : (Ht + (t - 32) * 9);
        float* dst = ws_inv + t * 9;
        // 3x3 inverse via adjugate, computed in double for conditioning.
        double a = src[0], b = src[1], c = src[2];
        double d = src[3], e = src[4], f = src[5];
        double g = src[6], h = src[7], i = src[8];
        double A = e * i - f * h;
        double Bc = c * h - b * i;
        double Cc = b * f - c * e;
        double D = f * g - d * i;
        double E = a * i - c * g;
        double F = c * d - a * f;
        double G = d * h - e * g;
        double Hh = b * g - a * h;
        double Ii = a * e - b * d;
        double idet = 1.0 / (a * A + b * D + c * G);
        // Fold the grid-normalization chain into rows 0/1:
        // xs = ((2X/(W-1)-1+1)*W-1)*0.5 = X*(W/(W-1)) - 0.5
        const double sc = (double)IMG_W / (double)(IMG_W - 1);  // 512/511 (H==W)
        dst[0] = (float)(A * idet * sc);
        dst[1] = (float)(Bc * idet * sc);
        dst[2] = (float)(Cc * idet * sc);
        dst[3] = (float)(D * idet * sc);
        dst[4] = (float)(E * idet * sc);
        dst[5] = (float)(F * idet * sc);
        dst[6] = (float)(G * idet);
        dst[7] = (float)(Hh * idet);
        dst[8] = (float)(Ii * idet);
    }
}

// Paired-corner sampling setup. The two x-adjacent corners of each bilinear
// row are fetched with ONE 8-byte load (4B-aligned; global loads tolerate
// this on gfx950 -- MUBUF dwordx2 does NOT, which broke R8).
// E[0]/E[1] = clamped element indices of the (y0,y1) row pairs.
// W[0..3]  = weights for (row0.slotA, row0.slotB, row1.slotA, row1.slotB).
// Validity lives ONLY in the weights. Two slot-swap cases:
//  - left edge x0==-1: pair loaded at xc0=0, x1 corner sits in slot A.
//  - clamp-down e==H*W-1 (image corner): x0 corner sits in slot B.
__device__ __forceinline__ void grid_setup_pair(float X, float Y, float Z,
                                                int* E, float* W) {
    const float iz = __builtin_amdgcn_rcpf(Z);
    const float xs = __builtin_fmaf(X, iz, -0.5f);
    const float ys = __builtin_fmaf(Y, iz, -0.5f);

    const float x0f = __builtin_floorf(xs);
    const float y0f = __builtin_floorf(ys);
    const int x0 = (int)x0f, y0 = (int)y0f;
    const int x1 = x0 + 1, y1 = y0 + 1;

    float wx1 = xs - x0f, wx0 = 1.0f - wx1;
    float wy1 = ys - y0f, wy0 = 1.0f - wy1;
    const float wx0m = ((unsigned)x0 < (unsigned)IMG_W) ? wx0 : 0.0f;
    const float wx1m = ((unsigned)x1 < (unsigned)IMG_W) ? wx1 : 0.0f;
    const float wy0m = ((unsigned)y0 < (unsigned)IMG_H) ? wy0 : 0.0f;
    const float wy1m = ((unsigned)y1 < (unsigned)IMG_H) ? wy1 : 0.0f;

    const bool sl = (x0 < 0);               // x0==-1 => x1 corner in slot A
    const float xA = sl ? wx1m : wx0m;      // (x0<=-2 => wx1m==0 too)
    const float xB = sl ? 0.0f : wx1m;
    const int xc0 = min(max(x0, 0), IMG_W - 1);

    const int e0r = y0 * IMG_W + xc0;       // may be far out of range
    const int e1r = e0r + IMG_W;
    const int emax = IMG_H * IMG_W - 2;     // pair [emax, emax+1] is last valid
    const int e0 = min(max(e0r, 0), emax);
    const int e1 = min(max(e1r, 0), emax);
    // Clamp fired? Either y-invalid (y-weight 0, slots irrelevant) or the
    // genuine e==H*W-1 corner case (clamp-down by 1: x0 value in slot B).
    const bool d0 = (e0 != e0r);
    const bool d1 = (e1 != e1r);
    const float uA0 = d0 ? 0.0f : xA, uB0 = d0 ? xA : xB;
    const float uA1 = d1 ? 0.0f : xA, uB1 = d1 ? xA : xB;

    E[0] = e0;
    E[1] = e1;
    W[0] = uA0 * wy0m; W[1] = uB0 * wy0m;
    W[2] = uA1 * wy1m; W[3] = uB1 * wy1m;
}

// 8-byte load at 4-byte alignment: memcpy -> load <2 x float> align 4 ->
// global_load_dwordx2 (gfx950 supports unaligned global access).
__device__ __forceinline__ float2 load_pair(const float* p) {
    float2 r;
    __builtin_memcpy(&r, p, 8);
    return r;
}

// 2 px/thread; __launch_bounds__(256,4) caps VGPR at 128 (4 waves/EU).
__global__ __launch_bounds__(256, 4) void photoloss_main_kernel(
        const float* __restrict__ I,
        const float* __restrict__ ws_inv,
        float* __restrict__ partials) {
    const int b = blockIdx.y;
    const int row = blockIdx.x;            // one full image row per block
    const int t = threadIdx.x;
    const float fy = (float)row;
    const float fx0 = (float)t;
    const float fx1 = (float)(t + 256);

    const float* __restrict__ hp = ws_inv + b * 9;          // pred inverse (rows 0/1 pre-scaled)
    const float* __restrict__ ht = ws_inv + (b + 32) * 9;   // true inverse

    // y-dependent part of each homography row is shared by both pixels
    const float cxp = __builtin_fmaf(hp[1], fy, hp[2]);
    const float cyp = __builtin_fmaf(hp[4], fy, hp[5]);
    const float czp = __builtin_fmaf(hp[7], fy, hp[8]);
    const float cxt = __builtin_fmaf(ht[1], fy, ht[2]);
    const float cyt = __builtin_fmaf(ht[4], fy, ht[5]);
    const float czt = __builtin_fmaf(ht[7], fy, ht[8]);

    // combo j: 0=px0-pred, 1=px0-true, 2=px1-pred, 3=px1-true
    int   Eoff[8];    // [2j] = row-y0 pair element index, [2j+1] = row-y1
    float W[16];      // [4j..4j+3] = weights for that combo's 4 corners
    grid_setup_pair(__builtin_fmaf(hp[0], fx0, cxp), __builtin_fmaf(hp[3], fx0, cyp),
                    __builtin_fmaf(hp[6], fx0, czp), Eoff + 0, W + 0);
    grid_setup_pair(__builtin_fmaf(ht[0], fx0, cxt), __builtin_fmaf(ht[3], fx0, cyt),
                    __builtin_fmaf(ht[6], fx0, czt), Eoff + 2, W + 4);
    grid_setup_pair(__builtin_fmaf(hp[0], fx1, cxp), __builtin_fmaf(hp[3], fx1, cyp),
                    __builtin_fmaf(hp[6], fx1, czp), Eoff + 4, W + 8);
    grid_setup_pair(__builtin_fmaf(ht[0], fx1, cxt), __builtin_fmaf(ht[3], fx1, cyt),
                    __builtin_fmaf(ht[6], fx1, czt), Eoff + 6, W + 12);

    // Per-pair predicate: pair k (combo j=k>>1, row rr=k&1) carries weights
    // W[4j+2rr], W[4j+2rr+1] (both nonneg). If their sum is 0 the pair
    // contributes v*0 only -> skip its loads. EXEC-masked lanes generate NO
    // TA requests, and the gather path is per-dword throughput-bound (R7/R9:
    // ~8.5 cyc/dword conserved across repacking). Wild warps (Z = 1 +
    // N(0,0.05)*coord) put large regions fully OOB -> big dword savings.
    bool pred[8];
#pragma unroll
    for (int k = 0; k < 8; ++k) {
        const int j = k >> 1, rr = k & 1;
        pred[k] = (W[4 * j + 2 * rr] + W[4 * j + 2 * rr + 1]) > 0.0f;
    }

    const float* __restrict__ ch0 = I + ((size_t)b * IMG_C << HW_SHIFT);
    const float* __restrict__ ch1 = ch0 + ((size_t)1 << HW_SHIFT);
    const float* __restrict__ ch2 = ch0 + ((size_t)2 << HW_SHIFT);

    // Batch the (predicated) paired loads; one predicate serves all 3
    // channels, so 8 exec-toggles guard 24 loads.
    float2 r[24];
#pragma unroll
    for (int k = 0; k < 8; ++k) {
        float2 v0 = make_float2(0.0f, 0.0f);
        float2 v1 = v0;
        float2 v2 = v0;
        if (pred[k]) {
            v0 = load_pair(ch0 + Eoff[k]);
            v1 = load_pair(ch1 + Eoff[k]);
            v2 = load_pair(ch2 + Eoff[k]);
        }
        r[0 * 8 + k] = v0;
        r[1 * 8 + k] = v1;
        r[2 * 8 + k] = v2;
    }

    float lsum = 0.0f;
#pragma unroll
    for (int c = 0; c < IMG_C; ++c) {
        const float2* rc = r + c * 8;
        const float sp0 = rc[0].x * W[0]  + rc[0].y * W[1]  + rc[1].x * W[2]  + rc[1].y * W[3];
        const float st0 = rc[2].x * W[4]  + rc[2].y * W[5]  + rc[3].x * W[6]  + rc[3].y * W[7];
        const float sp1 = rc[4].x * W[8]  + rc[4].y * W[9]  + rc[5].x * W[10] + rc[5].y * W[11];
        const float st1 = rc[6].x * W[12] + rc[6].y * W[13] + rc[7].x * W[14] + rc[7].y * W[15];
        const float d0 = sp0 - st0;
        const float d1 = sp1 - st1;
        lsum = __builtin_fmaf(d0, d0, lsum);
        lsum = __builtin_fmaf(d1, d1, lsum);
    }

    // wave (64-lane) reduction
#pragma unroll
    for (int off = 32; off > 0; off >>= 1)
        lsum += __shfl_down(lsum, off, 64);

    __shared__ float wsum[4];
    const int lane = threadIdx.x & 63;
    const int wid = threadIdx.x >> 6;
    if (lane == 0) wsum[wid] = lsum;
    __syncthreads();
    if (threadIdx.x == 0) {
        // One coalesced store per block -- NO atomics (same-address fp64
        // atomicAdd serialized the whole grid at ~400 us in R1/R2).
        partials[blockIdx.y * gridDim.x + blockIdx.x] = wsum[0] + wsum[1] + wsum[2] + wsum[3];
    }
}

__global__ __launch_bounds__(1024) void photoloss_reduce_kernel(
        const float* __restrict__ partials, float* __restrict__ out) {
    // Single block, 1024 threads = 16 waves; 16 partials per thread.
    double s = 0.0;
    for (int i = threadIdx.x; i < NPARTIALS; i += 1024)
        s += (double)partials[i];
#pragma unroll
    for (int off = 32; off > 0; off >>= 1)
        s += __shfl_down(s, off, 64);

    __shared__ double wsum[16];
    const int lane = threadIdx.x & 63;
    const int wid = threadIdx.x >> 6;
    if (lane == 0) wsum[wid] = s;
    __syncthreads();
    if (threadIdx.x == 0) {
        double total = 0.0;
#pragma unroll
        for (int i = 0; i < 16; ++i) total += wsum[i];
        const double n = (double)IMG_B * IMG_C * IMG_H * IMG_W;  // 25165824
        out[0] = (float)(total / n);
    }
}

extern "C" void kernel_launch(void* const* d_in, const int* in_sizes, int n_in,
                              void* d_out, int out_size, void* d_ws, size_t ws_size,
                              hipStream_t stream) {
    const float* Hp = (const float*)d_in[0];
    const float* Ht = (const float*)d_in[1];
    const float* I  = (const float*)d_in[2];
    float* out = (float*)d_out;

    float* ws_inv = (float*)d_ws;
    float* partials = (float*)((char*)d_ws + WS_PART_OFFSET);

    photoloss_invert_kernel<<<1, 64, 0, stream>>>(Hp, Ht, ws_inv);

    dim3 grid(NBLOCKS_X, IMG_B);  // (512, 32), natural order (R6 XCD swizzle regressed)
    photoloss_main_kernel<<<grid, 256, 0, stream>>>(I, ws_inv, partials);

    photoloss_reduce_kernel<<<1, 1024, 0, stream>>>(partials, out);
}